// Round 1
// baseline (110.542 us; speedup 1.0000x reference)
//
#include <hip/hip_runtime.h>

typedef _Float16 half8 __attribute__((ext_vector_type(8)));
typedef _Float16 half4v __attribute__((ext_vector_type(4)));
typedef float floatx4 __attribute__((ext_vector_type(4)));
typedef unsigned int uint2v __attribute__((ext_vector_type(2)));

#define NSPLIT 64
#define KS 64
#define DIM 2048
#define NROW 128            // 2*KS rows of T per split
#define BK 128              // k-panel width
#define KSPL 4              // k-chunks per split -> 256 blocks
#define KCH (DIM / KSPL)    // 512
#define NKC_A (KCH / BK)    // 4 panels per block
#define SST 152             // stage row stride (fp16): 304 B, 16B-aligned, 2-way banks (free)
#define GSZ (NROW * NROW)   // 16384 halfs per partial-gram slab (fp16)
#define NBLK (NSPLIT * KSPL)            // 256 blocks
// float-index offsets into ws (slabs are halfs: NBLK*GSZ/2 floats)
#define GT2F_OFF (NBLK * GSZ / 2)       // per-block sum-of-gram scalars (256 floats)
#define PART_OFF (GT2F_OFF + NBLK)      // per-reduce-block partials (256 x float4)
#define CNT_OFF (PART_OFF + NBLK * 4)   // last-block-done counter (1 u32)

// Slab layout fragment-major (half index): idx = wave*1024 + acc*256 + lane*4 + reg
// wave = (row>>5)*4 + (col>>5); acc = ((row>>4)&1)*2 + ((col>>4)&1);
// lane = ((row&15)>>2)*16 + (col&15); reg = row&3.
// => rows 32*rb..32*rb+31 of a slab are the contiguous 4 KB half-range
//    [rb*4096, rb*4096+4096): coalesced strip reads in the reduce phase.

__device__ __forceinline__ unsigned int pk16(float a, float b) {
  return __builtin_bit_cast(unsigned int, __builtin_amdgcn_cvt_pkrtz(a, b));
}

// ---- Kernel A: partial gram over one 512-wide k-chunk. grid = 256.
// Double-buffered LDS staging: ONE barrier per panel; loads for panel k+1 are
// in flight across the barrier and panel-k MFMA. No atomics, no fences.
__global__ __launch_bounds__(1024) void gram_kernel(const float* __restrict__ src,
                                                    const float* __restrict__ tgt,
                                                    float* __restrict__ ws) {
  __shared__ __align__(16) _Float16 stage[2][NROW * SST];  // 2 x ~38 KB
  __shared__ float red[16];

  // zero the reduce kernel's last-block counter (visible via dispatch boundary)
  if (blockIdx.x == 0 && threadIdx.x == 0) *(unsigned*)(ws + CNT_OFF) = 0u;

  const int p = blockIdx.x >> 2;
  const int c = blockIdx.x & (KSPL - 1);
  const int tid = threadIdx.x;
  const int lane = tid & 63;
  const int wave = tid >> 6;

  const int srow = tid >> 3;
  const int c4 = (tid & 7) * 4;
  const float* rowp = ((srow < KS) ? (src + (size_t)(p * KS + srow) * DIM)
                                   : (tgt + (size_t)(p * KS + (srow - KS)) * DIM)) +
                      c * KCH;

  const int wr = (wave >> 2) * 32;
  const int wc = (wave & 3) * 32;
  const int fr = lane & 15;
  const int fk = (lane >> 4) * 8;

  floatx4 acc00 = {0.f, 0.f, 0.f, 0.f};
  floatx4 acc01 = {0.f, 0.f, 0.f, 0.f};
  floatx4 acc10 = {0.f, 0.f, 0.f, 0.f};
  floatx4 acc11 = {0.f, 0.f, 0.f, 0.f};

  float4 f0, f1, f2, f3;
#define LOADK(kc)                                      \
  do {                                                 \
    const float* gp_ = rowp + (kc) * BK + c4;          \
    f0 = *(const float4*)(gp_);                        \
    f1 = *(const float4*)(gp_ + 32);                   \
    f2 = *(const float4*)(gp_ + 64);                   \
    f3 = *(const float4*)(gp_ + 96);                   \
  } while (0)

  LOADK(0);
#pragma unroll
  for (int kc = 0; kc < NKC_A; ++kc) {
    // convert + store panel kc into buf[kc&1] (waits on its loads only)
    {
      _Float16* sp = &stage[kc & 1][srow * SST + c4];
      *(uint2v*)(sp)      = (uint2v){pk16(f0.x, f0.y), pk16(f0.z, f0.w)};
      *(uint2v*)(sp + 32) = (uint2v){pk16(f1.x, f1.y), pk16(f1.z, f1.w)};
      *(uint2v*)(sp + 64) = (uint2v){pk16(f2.x, f2.y), pk16(f2.z, f2.w)};
      *(uint2v*)(sp + 96) = (uint2v){pk16(f3.x, f3.y), pk16(f3.z, f3.w)};
    }
    if (kc + 1 < NKC_A) LOADK(kc + 1);  // issue next panel's loads pre-barrier
    __syncthreads();                    // buf[kc&1] complete for all waves
    // safety: storing buf[(kc+2)&1] requires passing barrier kc+1, and per-wave
    // program order (MFMA kc precedes store kc+1) => all reads of buf[kc&1] done.
    const _Float16* sbuf = stage[kc & 1];
#pragma unroll
    for (int ks = 0; ks < 4; ++ks) {
      const int ko = ks * 32 + fk;
      half8 a0 = *(const half8*)&sbuf[(wr + fr) * SST + ko];
      half8 a1 = *(const half8*)&sbuf[(wr + 16 + fr) * SST + ko];
      half8 b0 = *(const half8*)&sbuf[(wc + fr) * SST + ko];
      half8 b1 = *(const half8*)&sbuf[(wc + 16 + fr) * SST + ko];
      acc00 = __builtin_amdgcn_mfma_f32_16x16x32_f16(a0, b0, acc00, 0, 0, 0);
      acc01 = __builtin_amdgcn_mfma_f32_16x16x32_f16(a0, b1, acc01, 0, 0, 0);
      acc10 = __builtin_amdgcn_mfma_f32_16x16x32_f16(a1, b0, acc10, 0, 0, 0);
      acc11 = __builtin_amdgcn_mfma_f32_16x16x32_f16(a1, b1, acc11, 0, 0, 0);
    }
  }
#undef LOADK

  // fp16 fragment-major slab store: 4x contiguous 512B/wave stores (RNE casts)
  _Float16* hs = (_Float16*)ws + (size_t)blockIdx.x * GSZ + wave * 1024 + lane * 4;
  {
    half4v h0, h1, h2, h3;
#pragma unroll
    for (int r = 0; r < 4; ++r) {
      h0[r] = (_Float16)acc00[r];
      h1[r] = (_Float16)acc01[r];
      h2[r] = (_Float16)acc10[r];
      h3[r] = (_Float16)acc11[r];
    }
    *(half4v*)(hs)       = h0;
    *(half4v*)(hs + 256) = h1;
    *(half4v*)(hs + 512) = h2;
    *(half4v*)(hs + 768) = h3;
  }

  // block-reduce fp32 sum of this partial gram -> ws[GT2F_OFF + b]
  float gsum = 0.0f;
#pragma unroll
  for (int r = 0; r < 4; ++r) gsum += acc00[r] + acc01[r] + acc10[r] + acc11[r];
#pragma unroll
  for (int m = 1; m <= 32; m <<= 1) gsum += __shfl_xor(gsum, m, 64);
  if (lane == 0) red[wave] = gsum;
  __syncthreads();
  if (tid == 0) {
    float t = 0.0f;
    for (int w = 0; w < 16; ++w) t += red[w];
    ws[GT2F_OFF + blockIdx.x] = t;
  }
}

// ---- Kernel B: 4 blocks per split (32 rows each), grid = 256. Coalesced
// fragment-order strip reads; l2/exp evaluated directly in fragment order
// (reduction is order-free). Last-finishing block folds in the final combine.
__global__ __launch_bounds__(1024) void reduce_kernel(float* __restrict__ ws,
                                                      float* __restrict__ out) {
  __shared__ float sqv[NROW];
  __shared__ float bcast[8];
  __shared__ float redm[16];
  __shared__ float redq[16];
  __shared__ float fr2[16][5];
  __shared__ unsigned amLast;

  const int b = blockIdx.x;
  const int p = b >> 2;
  const int rb = b & 3;
  const int tid = threadIdx.x;
  const int lane = tid & 63;
  const int wave = tid >> 6;

  const _Float16* sb = (const _Float16*)ws + (size_t)(p * KSPL) * GSZ;

  // Bulk coalesced read: this block's 32 gram rows = slab waves 4rb..4rb+3,
  // one contiguous 8 KB run per slab. Thread t owns fragment slot t:
  // 4 halfs = rows r0..r0+3 of one column. Sum the 4 k-chunk slabs in c8 order
  // (same element order as the old scattered path -> identical fp32 values).
  const int hoff = rb * 4096 + tid * 4;
  float g0, g1, g2, g3;
  {
    half4v h = *(const half4v*)(sb + hoff);
    g0 = (float)h[0]; g1 = (float)h[1]; g2 = (float)h[2]; g3 = (float)h[3];
#pragma unroll
    for (int c8 = 1; c8 < KSPL; ++c8) {
      half4v hh = *(const half4v*)(sb + (size_t)c8 * GSZ + hoff);
      g0 += (float)hh[0]; g1 += (float)hh[1]; g2 += (float)hh[2]; g3 += (float)hh[3];
    }
  }

  // diagonal (sq): same fp16 values + same sum order as strips -> l2_ii exactly 0
  if (tid < NROW) {
    const int i = tid;
    const int wd = (i >> 5) * 5;
    const int ad = ((i >> 4) & 1) * 3;
    const int lnd = (((i & 15) >> 2) << 4) + (i & 15);
    const int idxd = wd * 1024 + ad * 256 + lnd * 4 + (i & 3);
    float d = 0.0f;
#pragma unroll
    for (int c8 = 0; c8 < KSPL; ++c8) d += (float)sb[(size_t)c8 * GSZ + idxd];
    sqv[i] = d;
  }
  __syncthreads();

  if (tid == 0) {
    float ssq = 0.0f;
    for (int i = 0; i < NROW; ++i) ssq += sqv[i];
    float gt = ws[GT2F_OFF + p * 4 + 0] + ws[GT2F_OFF + p * 4 + 1] +
               ws[GT2F_OFF + p * 4 + 2] + ws[GT2F_OFF + p * 4 + 3];
    float suml2 = 2.0f * (float)NROW * ssq - 2.0f * gt;      // sum(l2) identity
    float bw = suml2 / (float)(NROW * NROW - NROW) * 0.25f;  // /(n^2-n) /KERNEL_MUL^2
    float mult = 1.0f;
    for (int k = 0; k < 5; ++k) {
      bcast[k] = 1.0f / (bw * mult + 1e-9f);
      mult *= 2.0f;
    }
  }
  __syncthreads();

  // decode (row,col) of this thread's fragment slot:
  // row = rb*32 + bit7(t)*16 + bits5..4(t)*4 + k ; col = bits9..8(t)*32 + bit6(t)*16 + bits3..0(t)
  const int r0 = rb * 32 + ((tid >> 7) & 1) * 16 + ((tid >> 4) & 3) * 4;
  const int col = (tid >> 8) * 32 + ((tid >> 6) & 1) * 16 + (tid & 15);
  const float sqc = sqv[col];
  const floatx4 sr = *(const floatx4*)&sqv[r0];  // rows r0..r0+3: one b128, 16B aligned
  const float gg[4] = {g0, g1, g2, g3};
  float l2r[4];
  float lmax = 0.0f;
#pragma unroll
  for (int k = 0; k < 4; ++k) {
    float v = sr[k] + sqc - 2.0f * gg[k];
    l2r[k] = v;
    lmax = fmaxf(lmax, v);
  }
#pragma unroll
  for (int m = 1; m <= 32; m <<= 1) lmax = fmaxf(lmax, __shfl_xor(lmax, m, 64));
  if (lane == 0) redm[wave] = lmax;

  const float ib0 = bcast[0], ib1 = bcast[1], ib2 = bcast[2], ib3 = bcast[3], ib4 = bcast[4];
  float qsum = 0.0f;
#pragma unroll
  for (int k = 0; k < 4; ++k) {
    float v = l2r[k];
    qsum += __expf(-v * ib0) + __expf(-v * ib1) + __expf(-v * ib2) +
            __expf(-v * ib3) + __expf(-v * ib4);
  }
  // whole wave shares one col-half: waves 0..7 -> X cols, 8..15 -> Y cols
#pragma unroll
  for (int m = 1; m <= 32; m <<= 1) qsum += __shfl_xor(qsum, m, 64);
  if (lane == 0) redq[wave] = qsum;
  __syncthreads();

  if (tid == 0) {
    float qX = 0.0f, qY = 0.0f, mx = 0.0f;
#pragma unroll
    for (int w = 0; w < 8; ++w) qX += redq[w];
#pragma unroll
    for (int w = 8; w < 16; ++w) qY += redq[w];
#pragma unroll
    for (int w = 0; w < 16; ++w) mx = fmaxf(mx, redm[w]);
    float4* part = (float4*)(ws + PART_OFF);
    part[b] = make_float4(qX, qY, mx, 0.0f);
    __threadfence();  // release: partial visible before counter tick
    unsigned old = atomicAdd((unsigned*)(ws + CNT_OFF), 1u);
    amLast = (old == NBLK - 1) ? 1u : 0u;
  }
  __syncthreads();

  if (amLast) {  // block-uniform branch
    __threadfence();  // acquire: see all 256 partials
    const float4* part = (const float4*)(ws + PART_OFF);
    float xx = 0.f, xy = 0.f, yx = 0.f, yy = 0.f, mx = 0.f;
    if (tid < NBLK) {
      float4 pt = part[tid];
      const int rb2 = tid & 3;
      xx = (rb2 < 2) ? pt.x : 0.0f;
      xy = (rb2 < 2) ? pt.y : 0.0f;
      yx = (rb2 >= 2) ? pt.x : 0.0f;
      yy = (rb2 >= 2) ? pt.y : 0.0f;
      mx = ((tid >> 2) == NSPLIT - 1) ? pt.z : 0.0f;
    }
#pragma unroll
    for (int m = 1; m <= 32; m <<= 1) {
      xx += __shfl_xor(xx, m, 64);
      xy += __shfl_xor(xy, m, 64);
      yx += __shfl_xor(yx, m, 64);
      yy += __shfl_xor(yy, m, 64);
      mx = fmaxf(mx, __shfl_xor(mx, m, 64));
    }
    if (lane == 0) {
      fr2[wave][0] = xx; fr2[wave][1] = xy; fr2[wave][2] = yx; fr2[wave][3] = yy; fr2[wave][4] = mx;
    }
    __syncthreads();
    if (tid == 0) {
      float sxx = 0, sxy = 0, syx = 0, syy = 0, smx = 0;
      for (int w = 0; w < 16; ++w) {
        sxx += fr2[w][0]; sxy += fr2[w][1]; syx += fr2[w][2]; syy += fr2[w][3];
        smx = fmaxf(smx, fr2[w][4]);
      }
      const float inv = 1.0f / (4096.0f * 64.0f);  // /(64*64) then /P
      out[0] = (sxx + syy - sxy - syx) * inv;
      out[1] = smx;
      out[2] = sxx * inv;
      out[3] = syy * inv;
      out[4] = sxy * inv;
      out[5] = syx * inv;
    }
  }
}

extern "C" void kernel_launch(void* const* d_in, const int* in_sizes, int n_in,
                              void* d_out, int out_size, void* d_ws, size_t ws_size,
                              hipStream_t stream) {
  const float* src = (const float*)d_in[0];
  const float* tgt = (const float*)d_in[1];
  float* out = (float*)d_out;
  float* ws = (float*)d_ws;  // fp16 slabs 8.4 MB + gsum + partials + counter
  gram_kernel<<<NBLK, 1024, 0, stream>>>(src, tgt, ws);
  reduce_kernel<<<NBLK, 1024, 0, stream>>>(ws, out);
}